// Round 1
// baseline (4657.957 us; speedup 1.0000x reference)
//
#include <hip/hip_runtime.h>
#include <cstdint>
#include <cstddef>

#define B_SZ 32
#define NPTS 16384
#define NSAMP 2048
#define F_IN 64
#define C_IN 67
#define D_OUT 128
#define FPS_THREADS 1024
#define PPT (NPTS / FPS_THREADS)   // 16 points per thread

// ---------------------------------------------------------------------------
// Kernel 1: farthest point sampling. One block per batch, 1024 threads.
// Points live in registers (16 per thread). Distance math uses explicit
// round-to-nearest ops (no FMA contraction) to bit-match the reference;
// argmax tie-break = lowest index (first occurrence), matching jnp.argmax.
// ---------------------------------------------------------------------------
__global__ __launch_bounds__(FPS_THREADS, 4)
void fps_kernel(const float* __restrict__ xyz,       // [B, N, 3]
                const int* __restrict__ init_far,    // [B]
                int* __restrict__ idx_out,           // [B, S]
                float* __restrict__ newxyz_out)      // [B, S, 3]
{
    const int b = blockIdx.x;
    const int tid = threadIdx.x;
    const float* base = xyz + (size_t)b * NPTS * 3;

    float px[PPT], py[PPT], pz[PPT], dist[PPT];
#pragma unroll
    for (int p = 0; p < PPT; ++p) {
        const int i = tid + p * FPS_THREADS;
        px[p] = base[i * 3 + 0];
        py[p] = base[i * 3 + 1];
        pz[p] = base[i * 3 + 2];
        dist[p] = 1e10f;
    }

    __shared__ float s_cx, s_cy, s_cz;
    __shared__ int   s_fidx;
    __shared__ float s_wval[16];
    __shared__ int   s_widx[16];

    if (tid == 0) {
        const int f = init_far[b];
        s_fidx = f;
        s_cx = base[f * 3 + 0];
        s_cy = base[f * 3 + 1];
        s_cz = base[f * 3 + 2];
    }
    __syncthreads();

    const int lane = tid & 63;
    const int wave = tid >> 6;

    for (int s = 0; s < NSAMP; ++s) {
        const float cx = s_cx, cy = s_cy, cz = s_cz;
        // record BEFORE update (reference scan semantics)
        if (tid == 0) {
            const int f = s_fidx;
            idx_out[b * NSAMP + s] = f;
            float* o = newxyz_out + (size_t)(b * NSAMP + s) * 3;
            o[0] = cx; o[1] = cy; o[2] = cz;
        }

        float best = -1.0f;
        int   bi   = 0x7fffffff;
#pragma unroll
        for (int p = 0; p < PPT; ++p) {
            const float dx = __fsub_rn(px[p], cx);
            const float dy = __fsub_rn(py[p], cy);
            const float dz = __fsub_rn(pz[p], cz);
            const float d  = __fadd_rn(__fadd_rn(__fmul_rn(dx, dx),
                                                 __fmul_rn(dy, dy)),
                                       __fmul_rn(dz, dz));
            const float nd = fminf(dist[p], d);
            dist[p] = nd;
            // indices increase with p, so '>' keeps the lowest index on ties
            if (nd > best) { best = nd; bi = tid + p * FPS_THREADS; }
        }

        // 64-lane butterfly argmax, tie -> lower index
#pragma unroll
        for (int off = 32; off >= 1; off >>= 1) {
            const float ov = __shfl_xor(best, off, 64);
            const int   oi = __shfl_xor(bi, off, 64);
            if (ov > best || (ov == best && oi < bi)) { best = ov; bi = oi; }
        }
        if (lane == 0) { s_wval[wave] = best; s_widx[wave] = bi; }
        __syncthreads();

        if (wave == 0) {
            float v  = (lane < 16) ? s_wval[lane] : -1.0f;
            int   vi = (lane < 16) ? s_widx[lane] : 0x7fffffff;
#pragma unroll
            for (int off = 8; off >= 1; off >>= 1) {
                const float ov = __shfl_xor(v, off, 64);
                const int   oi = __shfl_xor(vi, off, 64);
                if (ov > v || (ov == v && oi < vi)) { v = ov; vi = oi; }
            }
            if (lane == 0) {
                s_fidx = vi;
                s_cx = base[vi * 3 + 0];
                s_cy = base[vi * 3 + 1];
                s_cz = base[vi * 3 + 2];
            }
        }
        __syncthreads();   // protects s_c* / s_fidx for next iteration's readers
    }
}

// ---------------------------------------------------------------------------
// Kernel 2: gather selected rows, 1x1 conv (x @ W + b), ReLU.
// Block = 256 threads handles 16 samples x 128 outputs. W staged in LDS.
// ---------------------------------------------------------------------------
#define SAMP_PER_BLK 16

__global__ __launch_bounds__(256)
void gather_linear_relu_kernel(const float* __restrict__ xyz,    // [B,N,3]
                               const float* __restrict__ feats,  // [B,N,F]
                               const int* __restrict__ idx,      // [B*S]
                               const float* __restrict__ W,      // [67,128]
                               const float* __restrict__ bias,   // [128]
                               float* __restrict__ out)          // [B*S,128]
{
    __shared__ float sW[C_IN][D_OUT];          // 34,304 B
    __shared__ float sX[SAMP_PER_BLK][C_IN + 1];
    __shared__ float sB[D_OUT];

    const int tid = threadIdx.x;

    for (int i = tid; i < C_IN * D_OUT; i += 256)
        (&sW[0][0])[i] = W[i];
    if (tid < D_OUT) sB[tid] = bias[tid];

    const int gs0 = blockIdx.x * SAMP_PER_BLK;

    // gather: 16 threads per sample
    {
        const int si = tid >> 4;    // 0..15
        const int j  = tid & 15;
        const int gs = gs0 + si;
        const int b  = gs >> 11;    // / NSAMP
        const int pt = idx[gs];
        const float* frow = feats + ((size_t)b * NPTS + pt) * F_IN;
        const float* xrow = xyz   + ((size_t)b * NPTS + pt) * 3;
        for (int c = j; c < F_IN; c += 16) sX[si][c] = frow[c];
        if (j < 3) sX[si][F_IN + j] = xrow[j];
    }
    __syncthreads();

    const int d = tid & 127;
    const int g = tid >> 7;         // 0/1 -> sample group
    float acc[8];
#pragma unroll
    for (int k = 0; k < 8; ++k) acc[k] = 0.0f;

    for (int c = 0; c < C_IN; ++c) {
        const float w = sW[c][d];
#pragma unroll
        for (int k = 0; k < 8; ++k)
            acc[k] = fmaf(sX[g * 8 + k][c], w, acc[k]);
    }

    const float bv = sB[d];
#pragma unroll
    for (int k = 0; k < 8; ++k) {
        const int gs = gs0 + g * 8 + k;
        const float v = acc[k] + bv;
        out[(size_t)gs * D_OUT + d] = fmaxf(v, 0.0f);
    }
}

// ---------------------------------------------------------------------------
extern "C" void kernel_launch(void* const* d_in, const int* in_sizes, int n_in,
                              void* d_out, int out_size, void* d_ws, size_t ws_size,
                              hipStream_t stream) {
    const float* xyz      = (const float*)d_in[0];   // [32,16384,3]
    const float* feats    = (const float*)d_in[1];   // [32,16384,64]
    const int*   init_far = (const int*)d_in[2];     // [32]
    const float* W        = (const float*)d_in[3];   // [67,128]
    const float* bias     = (const float*)d_in[4];   // [128]

    float* out_newxyz = (float*)d_out;                       // [32,2048,3]
    float* out_conv   = (float*)d_out + (size_t)B_SZ * NSAMP * 3;  // [32,2048,128]
    int*   idx_ws     = (int*)d_ws;                          // [32*2048]

    fps_kernel<<<B_SZ, FPS_THREADS, 0, stream>>>(xyz, init_far, idx_ws, out_newxyz);

    const int nblocks = (B_SZ * NSAMP) / SAMP_PER_BLK;       // 4096
    gather_linear_relu_kernel<<<nblocks, 256, 0, stream>>>(
        xyz, feats, idx_ws, W, bias, out_conv);
}